// Round 7
// baseline (541.900 us; speedup 1.0000x reference)
//
#include <hip/hip_runtime.h>

typedef unsigned short u16;
typedef __attribute__((ext_vector_type(8))) short bh8;     // 8 bf16 MFMA A/B frag
typedef __attribute__((ext_vector_type(4))) float f4;      // MFMA C/D frag / float4
typedef __attribute__((ext_vector_type(4))) unsigned short us4;

#define T_SEQ 2048
#define NHEADS 16
#define DHEAD 64
#define WIN 256
#define NBLK 512

#define MF(a, b, c) __builtin_amdgcn_mfma_f32_16x16x32_bf16((a), (b), (c), 0, 0, 0)

__device__ __forceinline__ float bf2f(u16 u) {
  union { unsigned int i; float f; } v; v.i = ((unsigned int)u) << 16; return v.f;
}
__device__ __forceinline__ u16 f2bf(float f) {
  unsigned int u = __float_as_uint(f);
  u = u + 0x7fffu + ((u >> 16) & 1u);   // RNE
  return (u16)(u >> 16);
}
__device__ __forceinline__ void async16(const void* g, void* l) {
  void* gv = const_cast<void*>(g);
  __builtin_amdgcn_global_load_lds(
      (__attribute__((address_space(1))) void*)gv,
      (__attribute__((address_space(3))) void*)l, 16, 0, 0);
}

// Inline dtype probe: 1 if x[0..255] plausible as fp32. Wave-uniform (ballot).
__device__ __forceinline__ int is_f32_probe(const void* x) {
  const float* xf = (const float*)x;
  const int lane = threadIdx.x & 63;
  int bad = 0;
  #pragma unroll
  for (int u = 0; u < 4; ++u) {
    const float v = xf[lane * 4 + u];
    const float a = fabsf(v);
    bad |= (!(a < 64.f)) || (!(v == 0.f || a > 1e-30f));
  }
  return __any(bad) ? 0 : 1;
}

// ---- device-scope grid barrier (all NBLK blocks resident by construction) ----
__device__ __forceinline__ void gridbar(unsigned int* bar, unsigned int target) {
  __syncthreads();
  if (threadIdx.x == 0) {
    __hip_atomic_fetch_add(bar, 1u, __ATOMIC_ACQ_REL, __HIP_MEMORY_SCOPE_AGENT);
    while (__hip_atomic_load(bar, __ATOMIC_ACQUIRE, __HIP_MEMORY_SCOPE_AGENT) < target) {
      __builtin_amdgcn_s_sleep(8);
    }
  }
  __syncthreads();
  __threadfence();   // acquire for all threads (L1 inv for cross-XCD visibility)
}

// ---- 128x128 GEMM tile (bf16 A/B), body identical to the proven gemm_bt ----
__device__ __forceinline__ void gtile(
    const u16* __restrict__ A, const u16* __restrict__ Bt, void* __restrict__ C,
    int K, int lda, int ldc, int row0, int col0, bool cf32,
    u16* As, u16* Bs)
{
  const int tid  = threadIdx.x;
  const int lane = tid & 63;
  const int w    = tid >> 6;
  const int wm   = (w >> 1) * 64;
  const int wn   = (w & 1) * 64;
  const int quad = lane >> 4;
  const int l16  = lane & 15;

  f4 acc[4][4] = {};

  size_t aoff[4]; const u16* bsrc[4]; int lofs[4];
  #pragma unroll
  for (int s = 0; s < 4; ++s) {
    const int r  = s * 32 + (tid >> 3);
    const int gc = (tid & 7) ^ (r & 7);
    aoff[s] = (size_t)(row0 + r) * lda + gc * 8;
    bsrc[s] = Bt + (size_t)(col0 + r) * K + gc * 8;
    lofs[s] = s * 4096 + tid * 16;
  }

  for (int k0 = 0; k0 < K; k0 += 64) {
    __syncthreads();
    #pragma unroll
    for (int s = 0; s < 4; ++s) {
      async16(A + aoff[s] + k0, (char*)As + lofs[s]);
      async16(bsrc[s] + k0,     (char*)Bs + lofs[s]);
    }
    __builtin_amdgcn_s_waitcnt(0);
    __syncthreads();

    #pragma unroll
    for (int ks = 0; ks < 2; ++ks) {
      bh8 af[4], bf[4];
      #pragma unroll
      for (int i = 0; i < 4; ++i) {
        const int row = wm + i * 16 + l16;
        const int lc  = (ks * 4 + quad) ^ (row & 7);
        af[i] = *(const bh8*)(As + row * 64 + lc * 8);
      }
      #pragma unroll
      for (int j = 0; j < 4; ++j) {
        const int row = wn + j * 16 + l16;
        const int lc  = (ks * 4 + quad) ^ (row & 7);
        bf[j] = *(const bh8*)(Bs + row * 64 + lc * 8);
      }
      #pragma unroll
      for (int i = 0; i < 4; ++i)
        #pragma unroll
        for (int j = 0; j < 4; ++j)
          acc[i][j] = MF(af[i], bf[j], acc[i][j]);
    }
  }
  __syncthreads();   // protect LDS before caller reuses it

  #pragma unroll
  for (int i = 0; i < 4; ++i) {
    #pragma unroll
    for (int j = 0; j < 4; ++j) {
      const int rb = row0 + wm + i * 16 + quad * 4;
      const int cc = col0 + wn + j * 16 + l16;
      #pragma unroll
      for (int r = 0; r < 4; ++r) {
        if (cf32) ((float*)C)[(size_t)(rb + r) * ldc + cc] = acc[i][j][r];
        else      ((u16*)C)[(size_t)(rb + r) * ldc + cc]   = f2bf(acc[i][j][r]);
      }
    }
  }
}

// ---- 64-row attention vblock (proven round-3 body, mask-algebra version) ----
__device__ __forceinline__ void attn_vb(
    const u16* __restrict__ qkv, u16* __restrict__ att, int ldo,
    int qb, int h, int b, u16* Kt, u16* Vt, u16* Ps)
{
  const int tid  = threadIdx.x;
  const int lane = tid & 63;
  const int w    = tid >> 6;
  const int quad = lane >> 4;
  const int l16  = lane & 15;
  const int qs = qb * 64;

  const u16* base = qkv + (size_t)b * T_SEQ * 3072 + h * 64;

  const size_t qrowg = (size_t)(qs + w * 16 + l16) * 3072;
  bh8 qa0 = *(const bh8*)&base[qrowg + quad * 8];
  bh8 qa1 = *(const bh8*)&base[qrowg + 32 + quad * 8];
  #pragma unroll
  for (int u = 0; u < 8; ++u) {
    qa0[u] = (short)f2bf(bf2f((u16)qa0[u]) * 0.125f);
    qa1[u] = (short)f2bf(bf2f((u16)qa1[u]) * 0.125f);
  }

  f4 Oc[4] = {};
  float mst[4] = {-1e30f, -1e30f, -1e30f, -1e30f};
  float lst[4] = {0.f, 0.f, 0.f, 0.f};

  const int tmin = (qb >= 4) ? 0 : (4 - qb);
  const int c8  = (tid & 7) * 8;
  const int r0s = tid >> 3;

  for (int t = tmin; t < 5; ++t) {
    const int kt0 = qs - 256 + t * 64;
    const bool diag  = (t == 4);
    const bool ledge = (t == 0);
    const int kb_lo = ledge ? w : 0;
    const int kb_hi = diag  ? w : 3;
    __syncthreads();

    #pragma unroll
    for (int r = r0s; r < 64; r += 32) {
      *(bh8*)&Kt[r * 72 + c8] =
          *(const bh8*)&base[(size_t)(kt0 + r) * 3072 + 1024 + c8];
      bh8 v = *(const bh8*)&base[(size_t)(kt0 + r) * 3072 + 2048 + c8];
      const int kc = r >> 3, ki = r & 7;
      #pragma unroll
      for (int u = 0; u < 8; ++u) {
        const int d = c8 + u;
        Vt[d * 72 + ((kc ^ (d >> 3)) << 3) + ki] = (u16)v[u];
      }
    }
    __syncthreads();

    f4 S[4];
    #pragma unroll
    for (int kb = 0; kb < 4; ++kb) {
      if (kb < kb_lo || kb > kb_hi) {
        S[kb][0] = S[kb][1] = S[kb][2] = S[kb][3] = -1e30f;
      } else {
        const int krow = (kb * 16 + l16) * 72;
        bh8 kf0 = *(const bh8*)&Kt[krow + quad * 8];
        bh8 kf1 = *(const bh8*)&Kt[krow + 32 + quad * 8];
        f4 s = {};
        s = MF(qa0, kf0, s);
        s = MF(qa1, kf1, s);
        S[kb] = s;
      }
    }

    if (diag || ledge) {
      #pragma unroll
      for (int kb = 0; kb < 4; ++kb) {
        if (kb == w) {
          #pragma unroll
          for (int rr = 0; rr < 4; ++rr) {
            const int ii = quad * 4 + rr;
            const bool ok = diag ? (l16 <= ii) : (l16 > ii);
            if (!ok) S[kb][rr] = -1e30f;
          }
        }
      }
    }

    float tmax[4] = {-1e30f, -1e30f, -1e30f, -1e30f};
    #pragma unroll
    for (int kb = 0; kb < 4; ++kb)
      #pragma unroll
      for (int rr = 0; rr < 4; ++rr)
        tmax[rr] = fmaxf(tmax[rr], S[kb][rr]);
    #pragma unroll
    for (int off = 1; off < 16; off <<= 1)
      #pragma unroll
      for (int rr = 0; rr < 4; ++rr)
        tmax[rr] = fmaxf(tmax[rr], __shfl_xor(tmax[rr], off));

    const bool grew = (tmax[0] > mst[0] + 8.f) || (tmax[1] > mst[1] + 8.f) ||
                      (tmax[2] > mst[2] + 8.f) || (tmax[3] > mst[3] + 8.f);
    if (__any(grew)) {
      #pragma unroll
      for (int rr = 0; rr < 4; ++rr) {
        const float mnew = fmaxf(mst[rr], tmax[rr]);
        const float al = __expf(mst[rr] - mnew);
        mst[rr] = mnew;
        lst[rr] *= al;
        #pragma unroll
        for (int db = 0; db < 4; ++db) Oc[db][rr] *= al;
      }
    }

    float rsum[4] = {0.f, 0.f, 0.f, 0.f};
    const int swq = quad >> 1;
    #pragma unroll
    for (int kb = 0; kb < 4; ++kb) {
      const int kc = kb * 2 + (l16 >> 3);
      const int ki = l16 & 7;
      #pragma unroll
      for (int rr = 0; rr < 4; ++rr) {
        const float p = __expf(S[kb][rr] - mst[rr]);
        rsum[rr] += p;
        const int q = w * 16 + quad * 4 + rr;
        Ps[q * 72 + ((kc ^ swq) << 3) + ki] = f2bf(p);
      }
    }
    #pragma unroll
    for (int off = 1; off < 16; off <<= 1)
      #pragma unroll
      for (int rr = 0; rr < 4; ++rr)
        rsum[rr] += __shfl_xor(rsum[rr], off);
    #pragma unroll
    for (int rr = 0; rr < 4; ++rr)
      lst[rr] += rsum[rr];

    {
      const int q = w * 16 + l16;
      const int swp = (q >> 3) & 1;
      bh8 pa0 = *(const bh8*)&Ps[q * 72 + (((0 + quad) ^ swp) << 3)];
      bh8 pa1 = *(const bh8*)&Ps[q * 72 + (((4 + quad) ^ swp) << 3)];
      #pragma unroll
      for (int db = 0; db < 4; ++db) {
        const int d = db * 16 + l16;
        const int dsw = d >> 3;
        bh8 vb0 = *(const bh8*)&Vt[d * 72 + (((0 + quad) ^ dsw) << 3)];
        bh8 vb1 = *(const bh8*)&Vt[d * 72 + (((4 + quad) ^ dsw) << 3)];
        Oc[db] = MF(pa0, vb0, Oc[db]);
        Oc[db] = MF(pa1, vb1, Oc[db]);
      }
    }
  }
  __syncthreads();   // protect LDS before caller reuses it

  u16* obase = att + (size_t)b * T_SEQ * ldo + h * 64;
  #pragma unroll
  for (int rr = 0; rr < 4; ++rr) {
    const int i = qs + w * 16 + quad * 4 + rr;
    const float inv = 1.f / lst[rr];
    #pragma unroll
    for (int db = 0; db < 4; ++db)
      obase[(size_t)i * ldo + db * 16 + l16] = f2bf(Oc[db][rr] * inv);
  }
}

// ---------------- fused single-launch kernel ----------------
// 512 blocks x 256 thr; LDS 32KB, VGPR capped <=256 by launch_bounds(256,2)
// -> >=2 blocks/CU resident -> all 512 blocks co-resident -> gridbar safe.
// P0 prep -> P1 QKV gemm (3 tiles/blk) -> P2 attn (4 vblocks/blk) -> P3 outproj.
__global__ __launch_bounds__(256, 2) void fused(
    const void* __restrict__ x, const void* __restrict__ w_qkv,
    const void* __restrict__ w_out, void* __restrict__ out,
    u16* __restrict__ xbf, u16* __restrict__ wqkvT, u16* __restrict__ woutT,
    u16* __restrict__ qkv, u16* __restrict__ attb, unsigned int* bar)
{
  __shared__ alignas(16) u16 smem[2 * 128 * 64];   // 32 KB, aliased per phase
  const int bid = blockIdx.x;
  const int tid = threadIdx.x;
  const int isf = is_f32_probe(x);

  // ======== P0a: xconv (8 jobs/block; 4096 total) ========
  #pragma unroll
  for (int i = 0; i < 8; ++i) {
    const size_t e = (((size_t)(bid * 8 + i)) * 256 + tid) * 8;
    if (isf) {
      const float* f = (const float*)x;
      us4 o0, o1;
      #pragma unroll
      for (int u = 0; u < 4; ++u) { o0[u] = f2bf(f[e + u]); o1[u] = f2bf(f[e + 4 + u]); }
      *(us4*)&xbf[e] = o0; *(us4*)&xbf[e + 4] = o1;
    } else {
      *(us4*)&xbf[e]     = *(const us4*)&((const u16*)x)[e];
      *(us4*)&xbf[e + 4] = *(const us4*)&((const u16*)x)[e + 4];
    }
  }
  // ======== P0b: weight transposes (8 tiles/block; 4096 total) ========
  {
    u16 (*tile)[33] = (u16(*)[33])smem;
    const int tx4 = (tid & 7) * 4;
    const int iy  = tid >> 3;
    for (int i = 0; i < 8; ++i) {
      const int j = bid * 8 + i;
      const void* in; u16* outw; int C, bx, by;
      if (j < 3072) { in = w_qkv; outw = wqkvT; C = 3072; bx = j % 96; by = j / 96; }
      else          { const int t = j - 3072; in = w_out; outw = woutT; C = 1024; bx = t % 32; by = t / 32; }
      const int y0 = by * 32;
      __syncthreads();
      if (isf) {
        f4 v = *(const f4*)&((const float*)in)[(size_t)(y0 + iy) * C + bx * 32 + tx4];
        #pragma unroll
        for (int u = 0; u < 4; ++u) tile[iy][tx4 + u] = f2bf(v[u]);
      } else {
        us4 v = *(const us4*)&((const u16*)in)[(size_t)(y0 + iy) * C + bx * 32 + tx4];
        #pragma unroll
        for (int u = 0; u < 4; ++u) tile[iy][tx4 + u] = v[u];
      }
      __syncthreads();
      const int i2 = tid >> 3;
      us4 o;
      #pragma unroll
      for (int u = 0; u < 4; ++u) o[u] = tile[tx4 + u][i2];
      *(us4*)&outw[(size_t)(bx * 32 + i2) * 1024 + y0 + tx4] = o;
    }
  }
  gridbar(bar, NBLK);

  // ======== P1: QKV gemm, 1536 tiles of 128x128 over [8192 x 3072] ========
  #pragma unroll
  for (int i = 0; i < 3; ++i) {
    const int t = bid + NBLK * i;
    gtile(xbf, wqkvT, qkv, 1024, 1024, 3072,
          (t / 24) * 128, (t % 24) * 128, false, smem, smem + 8192);
  }
  gridbar(bar, 2 * NBLK);

  // ======== P2: attention, 2048 vblocks (qb 32, h 16, b 4), 4/block ========
  #pragma unroll
  for (int i = 0; i < 4; ++i) {
    const int t = bid + NBLK * i;
    attn_vb(qkv, attb, 1024, t & 31, (t >> 5) & 15, t >> 9,
            smem, smem + 4608, smem + 9216);
  }
  gridbar(bar, 3 * NBLK);

  // ======== P3: out-proj, 512 tiles over [8192 x 1024] ========
  gtile(attb, woutT, out, 1024, 1024, 1024,
        (bid / 8) * 128, (bid % 8) * 128, isf != 0, smem, smem + 8192);
}

// ================= legacy fallback kernels (ws too small) =================
__global__ __launch_bounds__(256) void prep(
    const void* __restrict__ x, const void* __restrict__ w_qkv,
    const void* __restrict__ w_out, u16* __restrict__ xbf,
    u16* __restrict__ wqkvT, u16* __restrict__ woutT, int have_x)
{
  const int bid = blockIdx.x;
  const int tid = threadIdx.x;
  const int isf = is_f32_probe(x);

  if (bid < 4096) {
    if (!have_x) return;
    const size_t e = ((size_t)bid * 256 + tid) * 8;
    if (isf) {
      const float* f = (const float*)x;
      us4 o0, o1;
      #pragma unroll
      for (int u = 0; u < 4; ++u) { o0[u] = f2bf(f[e + u]); o1[u] = f2bf(f[e + 4 + u]); }
      *(us4*)&xbf[e] = o0; *(us4*)&xbf[e + 4] = o1;
    } else {
      *(us4*)&xbf[e]     = *(const us4*)&((const u16*)x)[e];
      *(us4*)&xbf[e + 4] = *(const us4*)&((const u16*)x)[e + 4];
    }
  } else {
    __shared__ alignas(16) u16 tile[32][33];
    const void* in; u16* out; int C, bx, by;
    if (bid < 4096 + 3072) { const int t = bid - 4096; in = w_qkv; out = wqkvT; C = 3072; bx = t % 96; by = t / 96; }
    else                   { const int t = bid - 7168; in = w_out; out = woutT; C = 1024; bx = t % 32; by = t / 32; }
    const int tx4 = (tid & 7) * 4;
    const int iy  = tid >> 3;
    const int y0 = by * 32;
    if (isf) {
      f4 v = *(const f4*)&((const float*)in)[(size_t)(y0 + iy) * C + bx * 32 + tx4];
      #pragma unroll
      for (int u = 0; u < 4; ++u) tile[iy][tx4 + u] = f2bf(v[u]);
    } else {
      us4 v = *(const us4*)&((const u16*)in)[(size_t)(y0 + iy) * C + bx * 32 + tx4];
      #pragma unroll
      for (int u = 0; u < 4; ++u) tile[iy][tx4 + u] = v[u];
    }
    __syncthreads();
    const int i2 = tid >> 3;
    us4 o;
    #pragma unroll
    for (int u = 0; u < 4; ++u) o[u] = tile[tx4 + u][i2];
    *(us4*)&out[(size_t)(bx * 32 + i2) * 1024 + y0 + tx4] = o;
  }
}

template<bool ADYN, bool CDYN>
__global__ __launch_bounds__(256, 4) void gemm_bt(
    const void* __restrict__ A, const u16* __restrict__ Bt,
    void* __restrict__ C, int N, int K, int lda, int ldc,
    const void* __restrict__ xprobe)
{
  __shared__ alignas(16) u16 As[128 * 64];
  __shared__ alignas(16) u16 Bs[128 * 64];

  const int isf  = (ADYN || CDYN) ? is_f32_probe(xprobe) : 0;
  const int tid  = threadIdx.x;
  const int lane = tid & 63;
  const int w    = tid >> 6;
  const int wm   = (w >> 1) * 64;
  const int wn   = (w & 1) * 64;
  const int quad = lane >> 4;
  const int l16  = lane & 15;
  const int row0 = blockIdx.y * 128;
  const int col0 = blockIdx.x * 128;

  f4 acc[4][4] = {};

  size_t aoff[4]; const u16* bsrc[4]; int lofs[4];
  #pragma unroll
  for (int s = 0; s < 4; ++s) {
    const int r  = s * 32 + (tid >> 3);
    const int gc = (tid & 7) ^ (r & 7);
    aoff[s] = (size_t)(row0 + r) * lda + gc * 8;
    bsrc[s] = Bt + (size_t)(col0 + r) * K + gc * 8;
    lofs[s] = s * 4096 + tid * 16;
  }

  const bool af32 = ADYN && isf;

  for (int k0 = 0; k0 < K; k0 += 64) {
    if (af32) {
      const float* Af = (const float*)A;
      bh8 a[4];
      #pragma unroll
      for (int s = 0; s < 4; ++s) {
        f4 u0 = *(const f4*)(Af + aoff[s] + k0);
        f4 u1 = *(const f4*)(Af + aoff[s] + k0 + 4);
        #pragma unroll
        for (int u = 0; u < 4; ++u) { a[s][u] = (short)f2bf(u0[u]); a[s][u + 4] = (short)f2bf(u1[u]); }
      }
      __syncthreads();
      #pragma unroll
      for (int s = 0; s < 4; ++s) {
        *(bh8*)((char*)As + lofs[s]) = a[s];
        async16(bsrc[s] + k0, (char*)Bs + lofs[s]);
      }
    } else {
      const u16* A16 = (const u16*)A;
      __syncthreads();
      #pragma unroll
      for (int s = 0; s < 4; ++s) {
        async16(A16 + aoff[s] + k0, (char*)As + lofs[s]);
        async16(bsrc[s] + k0,       (char*)Bs + lofs[s]);
      }
    }
    __builtin_amdgcn_s_waitcnt(0);
    __syncthreads();

    #pragma unroll
    for (int ks = 0; ks < 2; ++ks) {
      bh8 af[4], bf[4];
      #pragma unroll
      for (int i = 0; i < 4; ++i) {
        const int row = wm + i * 16 + l16;
        const int lc  = (ks * 4 + quad) ^ (row & 7);
        af[i] = *(const bh8*)(As + row * 64 + lc * 8);
      }
      #pragma unroll
      for (int j = 0; j < 4; ++j) {
        const int row = wn + j * 16 + l16;
        const int lc  = (ks * 4 + quad) ^ (row & 7);
        bf[j] = *(const bh8*)(Bs + row * 64 + lc * 8);
      }
      #pragma unroll
      for (int i = 0; i < 4; ++i)
        #pragma unroll
        for (int j = 0; j < 4; ++j)
          acc[i][j] = MF(af[i], bf[j], acc[i][j]);
    }
  }

  const bool cf32 = CDYN && isf;
  #pragma unroll
  for (int i = 0; i < 4; ++i) {
    #pragma unroll
    for (int j = 0; j < 4; ++j) {
      const int rb = row0 + wm + i * 16 + quad * 4;
      const int cc = col0 + wn + j * 16 + l16;
      #pragma unroll
      for (int r = 0; r < 4; ++r) {
        if (cf32) ((float*)C)[(size_t)(rb + r) * ldc + cc] = acc[i][j][r];
        else      ((u16*)C)[(size_t)(rb + r) * ldc + cc]   = f2bf(acc[i][j][r]);
      }
    }
  }
}

__global__ __launch_bounds__(256) void attn_legacy(const u16* __restrict__ qkv,
                                                   u16* __restrict__ att, int ldo)
{
  __shared__ alignas(16) u16 Kt[64 * 72];
  __shared__ alignas(16) u16 Vt[64 * 72];
  __shared__ alignas(16) u16 Ps[64 * 72];
  attn_vb(qkv, att, ldo, blockIdx.x, blockIdx.y, blockIdx.z, Kt, Vt, Ps);
}

// ---------------- launcher ----------------
extern "C" void kernel_launch(void* const* d_in, const int* in_sizes, int n_in,
                              void* d_out, int out_size, void* d_ws, size_t ws_size,
                              hipStream_t stream) {
  const void* x     = d_in[0];   // [8192, 1024]  fp32 or bf16 (auto-detected)
  const void* w_qkv = d_in[1];   // [1024, 3072]
  const void* w_out = d_in[2];   // [1024, 1024]

  const size_t SZ_QKV = (size_t)8192 * 3072 * 2;
  const size_t SZ_XBF = (size_t)8192 * 1024 * 2;
  const size_t SZ_WQ  = (size_t)3072 * 1024 * 2;
  const size_t SZ_WO  = (size_t)1024 * 1024 * 2;
  const size_t SZ_ATT = (size_t)8192 * 1024 * 2;

  char* p = (char*)d_ws;
  u16* qkv   = (u16*)p; p += SZ_QKV;
  u16* wqkvT = (u16*)p; p += SZ_WQ;
  u16* woutT = (u16*)p; p += SZ_WO;
  u16* xbf   = (u16*)p; p += SZ_XBF;
  u16* attb  = (u16*)p; p += SZ_ATT;
  unsigned int* bar = (unsigned int*)p; p += 256;

  const size_t need_x     = SZ_QKV + SZ_WQ + SZ_WO + SZ_XBF;
  const size_t need_fused = need_x + SZ_ATT + 256;
  const bool have_x     = ws_size >= need_x;
  const bool have_att   = ws_size >= need_x + SZ_ATT;
  const bool have_fused = ws_size >= need_fused;

  if (have_fused) {
    hipMemsetAsync(bar, 0, 64, stream);
    fused<<<dim3(NBLK), 256, 0, stream>>>(
        x, w_qkv, w_out, d_out, xbf, wqkvT, woutT, qkv, attb, bar);
    return;
  }

  // -------- legacy 4-kernel fallback --------
  prep<<<dim3(8192), 256, 0, stream>>>(x, w_qkv, w_out, xbf, wqkvT, woutT,
                                       have_x ? 1 : 0);
  if (have_x) {
    gemm_bt<false, false><<<dim3(24, 64), 256, 0, stream>>>(
        xbf, wqkvT, qkv, 3072, 1024, 1024, 3072, x);
  } else {
    gemm_bt<true, false><<<dim3(24, 64), 256, 0, stream>>>(
        x, wqkvT, qkv, 3072, 1024, 1024, 3072, x);
  }
  u16* attp = have_att ? attb : qkv;
  const int ldo = have_att ? 1024 : 3072;
  attn_legacy<<<dim3(32, NHEADS, 4), 256, 0, stream>>>(qkv, attp, ldo);
  gemm_bt<false, true><<<dim3(8, 64), 256, 0, stream>>>(
      attp, woutT, d_out, 1024, 1024, ldo, 1024, x);
}

// Round 8
// 302.515 us; speedup vs baseline: 1.7913x; 1.7913x over previous
//
#include <hip/hip_runtime.h>

typedef unsigned short u16;
typedef __attribute__((ext_vector_type(8))) short bh8;     // 8 bf16 MFMA A/B frag
typedef __attribute__((ext_vector_type(4))) float f4;      // MFMA C/D frag / float4
typedef __attribute__((ext_vector_type(4))) unsigned short us4;

#define T_SEQ 2048
#define NHEADS 16
#define DHEAD 64
#define WIN 256

#define MF(a, b, c) __builtin_amdgcn_mfma_f32_16x16x32_bf16((a), (b), (c), 0, 0, 0)

__device__ __forceinline__ float bf2f(u16 u) {
  union { unsigned int i; float f; } v; v.i = ((unsigned int)u) << 16; return v.f;
}
__device__ __forceinline__ u16 f2bf(float f) {
  unsigned int u = __float_as_uint(f);
  u = u + 0x7fffu + ((u >> 16) & 1u);   // RNE
  return (u16)(u >> 16);
}
__device__ __forceinline__ void async16(const void* g, void* l) {
  void* gv = const_cast<void*>(g);
  __builtin_amdgcn_global_load_lds(
      (__attribute__((address_space(1))) void*)gv,
      (__attribute__((address_space(3))) void*)l, 16, 0, 0);
}

// Inline dtype probe: 1 if x[0..255] plausible as fp32. Wave-uniform (ballot).
__device__ __forceinline__ int is_f32_probe(const void* x) {
  const float* xf = (const float*)x;
  const int lane = threadIdx.x & 63;
  int bad = 0;
  #pragma unroll
  for (int u = 0; u < 4; ++u) {
    const float v = xf[lane * 4 + u];
    const float a = fabsf(v);
    bad |= (!(a < 64.f)) || (!(v == 0.f || a > 1e-30f));
  }
  return __any(bad) ? 0 : 1;
}

// ---------------- prep: transpose(w_qkv) + transpose(w_out) only ----------------
// (xconv eliminated: QKV gemm reads fp32 x directly via its ADYN staging path.)
// Each thread: one f4/us4 load (4 cols) + one us4 store (4 transposed cols).
__global__ __launch_bounds__(256) void prep(
    const void* __restrict__ x, const void* __restrict__ w_qkv,
    const void* __restrict__ w_out, u16* __restrict__ wqkvT,
    u16* __restrict__ woutT)
{
  const int bid = blockIdx.x;
  const int tid = threadIdx.x;
  const int isf = is_f32_probe(x);

  __shared__ alignas(16) u16 tile[32][33];
  const void* in; u16* out; int C, bx, by;
  if (bid < 3072) { in = w_qkv; out = wqkvT; C = 3072; bx = bid % 96; by = bid / 96; }
  else            { const int t = bid - 3072; in = w_out; out = woutT; C = 1024; bx = t % 32; by = t / 32; }
  const int tx4 = (tid & 7) * 4;          // 4-col group
  const int iy  = tid >> 3;               // row in tile (0..31)
  const int y0 = by * 32;
  if (isf) {
    f4 v = *(const f4*)&((const float*)in)[(size_t)(y0 + iy) * C + bx * 32 + tx4];
    #pragma unroll
    for (int u = 0; u < 4; ++u) tile[iy][tx4 + u] = f2bf(v[u]);
  } else {
    us4 v = *(const us4*)&((const u16*)in)[(size_t)(y0 + iy) * C + bx * 32 + tx4];
    #pragma unroll
    for (int u = 0; u < 4; ++u) tile[iy][tx4 + u] = v[u];
  }
  __syncthreads();
  const int i2 = tid >> 3;
  us4 o;
  #pragma unroll
  for (int u = 0; u < 4; ++u) o[u] = tile[tx4 + u][i2];
  *(us4*)&out[(size_t)(bx * 32 + i2) * 1024 + y0 + tx4] = o;
}

// ---------------- bf16 GEMM, C[M,N] = A[M,K(lda)] * Bt[N,K]^T ----------------
// BK=64; 128x128 tile; 4 blocks/CU. LDS row = 128B (8 chunks of 16B); slot
// (row,c) holds GLOBAL chunk c ^ (row&7) -> conflict-free b128 frag reads.
// ADYN: A may be fp32 (probe-detected) -> in-register RNE cvt during staging.
template<bool ADYN, bool CDYN>
__global__ __launch_bounds__(256, 4) void gemm_bt(
    const void* __restrict__ A, const u16* __restrict__ Bt,
    void* __restrict__ C, int N, int K, int lda, int ldc,
    const void* __restrict__ xprobe)
{
  __shared__ alignas(16) u16 As[128 * 64];
  __shared__ alignas(16) u16 Bs[128 * 64];

  const int isf  = (ADYN || CDYN) ? is_f32_probe(xprobe) : 0;
  const int tid  = threadIdx.x;
  const int lane = tid & 63;
  const int w    = tid >> 6;
  const int wm   = (w >> 1) * 64;
  const int wn   = (w & 1) * 64;
  const int quad = lane >> 4;
  const int l16  = lane & 15;
  const int row0 = blockIdx.y * 128;
  const int col0 = blockIdx.x * 128;

  f4 acc[4][4] = {};

  size_t aoff[4]; const u16* bsrc[4]; int lofs[4];
  #pragma unroll
  for (int s = 0; s < 4; ++s) {
    const int r  = s * 32 + (tid >> 3);
    const int gc = (tid & 7) ^ (r & 7);
    aoff[s] = (size_t)(row0 + r) * lda + gc * 8;
    bsrc[s] = Bt + (size_t)(col0 + r) * K + gc * 8;
    lofs[s] = s * 4096 + tid * 16;
  }

  const bool af32 = ADYN && isf;

  for (int k0 = 0; k0 < K; k0 += 64) {
    if (af32) {
      const float* Af = (const float*)A;
      bh8 a[4];
      #pragma unroll
      for (int s = 0; s < 4; ++s) {
        f4 u0 = *(const f4*)(Af + aoff[s] + k0);
        f4 u1 = *(const f4*)(Af + aoff[s] + k0 + 4);
        #pragma unroll
        for (int u = 0; u < 4; ++u) { a[s][u] = (short)f2bf(u0[u]); a[s][u + 4] = (short)f2bf(u1[u]); }
      }
      __syncthreads();
      #pragma unroll
      for (int s = 0; s < 4; ++s) {
        *(bh8*)((char*)As + lofs[s]) = a[s];
        async16(bsrc[s] + k0, (char*)Bs + lofs[s]);
      }
    } else {
      const u16* A16 = (const u16*)A;
      __syncthreads();
      #pragma unroll
      for (int s = 0; s < 4; ++s) {
        async16(A16 + aoff[s] + k0, (char*)As + lofs[s]);
        async16(bsrc[s] + k0,       (char*)Bs + lofs[s]);
      }
    }
    __builtin_amdgcn_s_waitcnt(0);
    __syncthreads();

    #pragma unroll
    for (int ks = 0; ks < 2; ++ks) {
      bh8 af[4], bf[4];
      #pragma unroll
      for (int i = 0; i < 4; ++i) {
        const int row = wm + i * 16 + l16;
        const int lc  = (ks * 4 + quad) ^ (row & 7);
        af[i] = *(const bh8*)(As + row * 64 + lc * 8);
      }
      #pragma unroll
      for (int j = 0; j < 4; ++j) {
        const int row = wn + j * 16 + l16;
        const int lc  = (ks * 4 + quad) ^ (row & 7);
        bf[j] = *(const bh8*)(Bs + row * 64 + lc * 8);
      }
      #pragma unroll
      for (int i = 0; i < 4; ++i)
        #pragma unroll
        for (int j = 0; j < 4; ++j)
          acc[i][j] = MF(af[i], bf[j], acc[i][j]);
    }
  }

  const bool cf32 = CDYN && isf;
  #pragma unroll
  for (int i = 0; i < 4; ++i) {
    #pragma unroll
    for (int j = 0; j < 4; ++j) {
      const int rb = row0 + wm + i * 16 + quad * 4;
      const int cc = col0 + wn + j * 16 + l16;
      #pragma unroll
      for (int r = 0; r < 4; ++r) {
        if (cf32) ((float*)C)[(size_t)(rb + r) * ldc + cc] = acc[i][j][r];
        else      ((u16*)C)[(size_t)(rb + r) * ldc + cc]   = f2bf(acc[i][j][r]);
      }
    }
  }
}

// ---------------- MFMA flash-style sliding-window attention ----------------
// Verified round-2 body (211.3 us build). Q frags in registers (pre-scaled by
// 1/sqrt(d)); LDS = Kt+Vt+Ps = 27.6 KB -> 5 blocks/CU. Mask algebra: tiles
// t=1..3 unmasked; t=4 (diag) / t=0 (ledge) reduce to the kb==w sub-tile;
// fully-dead sub-tiles skip their QK MFMAs. Defer-max (T13) on the rescale.
__global__ __launch_bounds__(256) void attn_mfma(const u16* __restrict__ qkv,
                                                 u16* __restrict__ att, int ldo)
{
  __shared__ alignas(16) u16 Kt[64 * 72];
  __shared__ alignas(16) u16 Vt[64 * 72];   // (d,k): d*72 + ((k>>3)^(d>>3))*8 + (k&7)
  __shared__ alignas(16) u16 Ps[64 * 72];   // (q,k): q*72 + ((k>>3)^((q>>3)&1))*8 + (k&7)

  const int tid  = threadIdx.x;
  const int lane = tid & 63;
  const int w    = tid >> 6;
  const int quad = lane >> 4;
  const int l16  = lane & 15;
  const int qb = blockIdx.x, h = blockIdx.y, b = blockIdx.z;
  const int qs = qb * 64;

  const u16* base = qkv + (size_t)b * T_SEQ * 3072 + h * 64;

  const size_t qrowg = (size_t)(qs + w * 16 + l16) * 3072;
  bh8 qa0 = *(const bh8*)&base[qrowg + quad * 8];
  bh8 qa1 = *(const bh8*)&base[qrowg + 32 + quad * 8];
  #pragma unroll
  for (int u = 0; u < 8; ++u) {
    qa0[u] = (short)f2bf(bf2f((u16)qa0[u]) * 0.125f);
    qa1[u] = (short)f2bf(bf2f((u16)qa1[u]) * 0.125f);
  }

  f4 Oc[4] = {};
  float mst[4] = {-1e30f, -1e30f, -1e30f, -1e30f};
  float lst[4] = {0.f, 0.f, 0.f, 0.f};

  const int tmin = (qb >= 4) ? 0 : (4 - qb);
  const int c8  = (tid & 7) * 8;
  const int r0s = tid >> 3;

  for (int t = tmin; t < 5; ++t) {
    const int kt0 = qs - 256 + t * 64;
    const bool diag  = (t == 4);          // only j<=i can fail
    const bool ledge = (t == 0);          // only reached when qb>=4; only j>i-WIN can fail
    const int kb_lo = ledge ? w : 0;      // kb<w fully masked on left edge
    const int kb_hi = diag  ? w : 3;      // kb>w fully masked on diagonal
    __syncthreads();

    #pragma unroll
    for (int r = r0s; r < 64; r += 32) {
      *(bh8*)&Kt[r * 72 + c8] =
          *(const bh8*)&base[(size_t)(kt0 + r) * 3072 + 1024 + c8];
      bh8 v = *(const bh8*)&base[(size_t)(kt0 + r) * 3072 + 2048 + c8];
      const int kc = r >> 3, ki = r & 7;
      #pragma unroll
      for (int u = 0; u < 8; ++u) {
        const int d = c8 + u;
        Vt[d * 72 + ((kc ^ (d >> 3)) << 3) + ki] = (u16)v[u];
      }
    }
    __syncthreads();

    f4 S[4];
    #pragma unroll
    for (int kb = 0; kb < 4; ++kb) {
      if (kb < kb_lo || kb > kb_hi) {
        S[kb][0] = S[kb][1] = S[kb][2] = S[kb][3] = -1e30f;
      } else {
        const int krow = (kb * 16 + l16) * 72;
        bh8 kf0 = *(const bh8*)&Kt[krow + quad * 8];
        bh8 kf1 = *(const bh8*)&Kt[krow + 32 + quad * 8];
        f4 s = {};
        s = MF(qa0, kf0, s);
        s = MF(qa1, kf1, s);
        S[kb] = s;
      }
    }

    if (diag || ledge) {
      #pragma unroll
      for (int kb = 0; kb < 4; ++kb) {
        if (kb == w) {
          #pragma unroll
          for (int rr = 0; rr < 4; ++rr) {
            const int ii = quad * 4 + rr;
            const bool ok = diag ? (l16 <= ii) : (l16 > ii);
            if (!ok) S[kb][rr] = -1e30f;
          }
        }
      }
    }

    float tmax[4] = {-1e30f, -1e30f, -1e30f, -1e30f};
    #pragma unroll
    for (int kb = 0; kb < 4; ++kb)
      #pragma unroll
      for (int rr = 0; rr < 4; ++rr)
        tmax[rr] = fmaxf(tmax[rr], S[kb][rr]);
    #pragma unroll
    for (int off = 1; off < 16; off <<= 1)
      #pragma unroll
      for (int rr = 0; rr < 4; ++rr)
        tmax[rr] = fmaxf(tmax[rr], __shfl_xor(tmax[rr], off));

    // defer-max (T13): skip rescale while the running max grows < 8
    const bool grew = (tmax[0] > mst[0] + 8.f) || (tmax[1] > mst[1] + 8.f) ||
                      (tmax[2] > mst[2] + 8.f) || (tmax[3] > mst[3] + 8.f);
    if (__any(grew)) {
      #pragma unroll
      for (int rr = 0; rr < 4; ++rr) {
        const float mnew = fmaxf(mst[rr], tmax[rr]);
        const float al = __expf(mst[rr] - mnew);
        mst[rr] = mnew;
        lst[rr] *= al;
        #pragma unroll
        for (int db = 0; db < 4; ++db) Oc[db][rr] *= al;
      }
    }

    float rsum[4] = {0.f, 0.f, 0.f, 0.f};
    const int swq = quad >> 1;
    #pragma unroll
    for (int kb = 0; kb < 4; ++kb) {
      const int kc = kb * 2 + (l16 >> 3);
      const int ki = l16 & 7;
      #pragma unroll
      for (int rr = 0; rr < 4; ++rr) {
        const float p = __expf(S[kb][rr] - mst[rr]);  // masked: exp(-1e30)->0
        rsum[rr] += p;
        const int q = w * 16 + quad * 4 + rr;
        Ps[q * 72 + ((kc ^ swq) << 3) + ki] = f2bf(p);
      }
    }
    #pragma unroll
    for (int off = 1; off < 16; off <<= 1)
      #pragma unroll
      for (int rr = 0; rr < 4; ++rr)
        rsum[rr] += __shfl_xor(rsum[rr], off);
    #pragma unroll
    for (int rr = 0; rr < 4; ++rr)
      lst[rr] += rsum[rr];

    {
      const int q = w * 16 + l16;
      const int swp = (q >> 3) & 1;
      bh8 pa0 = *(const bh8*)&Ps[q * 72 + (((0 + quad) ^ swp) << 3)];
      bh8 pa1 = *(const bh8*)&Ps[q * 72 + (((4 + quad) ^ swp) << 3)];
      #pragma unroll
      for (int db = 0; db < 4; ++db) {
        const int d = db * 16 + l16;
        const int dsw = d >> 3;
        bh8 vb0 = *(const bh8*)&Vt[d * 72 + (((0 + quad) ^ dsw) << 3)];
        bh8 vb1 = *(const bh8*)&Vt[d * 72 + (((4 + quad) ^ dsw) << 3)];
        Oc[db] = MF(pa0, vb0, Oc[db]);
        Oc[db] = MF(pa1, vb1, Oc[db]);
      }
    }
  }

  u16* obase = att + (size_t)b * T_SEQ * ldo + h * 64;
  #pragma unroll
  for (int rr = 0; rr < 4; ++rr) {
    const int i = qs + w * 16 + quad * 4 + rr;
    const float inv = 1.f / lst[rr];
    #pragma unroll
    for (int db = 0; db < 4; ++db)
      obase[(size_t)i * ldo + db * 16 + l16] = f2bf(Oc[db][rr] * inv);
  }
}

// ---------------- launcher ----------------
extern "C" void kernel_launch(void* const* d_in, const int* in_sizes, int n_in,
                              void* d_out, int out_size, void* d_ws, size_t ws_size,
                              hipStream_t stream) {
  const void* x     = d_in[0];   // [8192, 1024]  fp32 or bf16 (auto-detected)
  const void* w_qkv = d_in[1];   // [1024, 3072]
  const void* w_out = d_in[2];   // [1024, 1024]

  const size_t SZ_QKV = (size_t)8192 * 3072 * 2;
  const size_t SZ_WQ  = (size_t)3072 * 1024 * 2;
  const size_t SZ_WO  = (size_t)1024 * 1024 * 2;
  const size_t SZ_ATT = (size_t)8192 * 1024 * 2;

  char* p = (char*)d_ws;
  u16* qkv   = (u16*)p; p += SZ_QKV;
  u16* wqkvT = (u16*)p; p += SZ_WQ;
  u16* woutT = (u16*)p; p += SZ_WO;
  u16* attb  = (u16*)p;
  const size_t need     = SZ_QKV + SZ_WQ + SZ_WO;
  const bool have_att   = ws_size >= need + SZ_ATT;

  // weight transposes only (xconv eliminated; gemm reads x directly)
  prep<<<dim3(4096), 256, 0, stream>>>(x, w_qkv, w_out, wqkvT, woutT);

  // QKV: ADYN path converts fp32 x -> bf16 in registers during A-staging
  gemm_bt<true, false><<<dim3(24, 64), 256, 0, stream>>>(
      x, wqkvT, qkv, 3072, 1024, 1024, 3072, x);

  // attention: compact output when ws allows, else in-place q-channel
  u16* attp  = have_att ? attb : qkv;
  const int ldo = have_att ? 1024 : 3072;
  attn_mfma<<<dim3(32, NHEADS, 4), 256, 0, stream>>>(qkv, attp, ldo);

  gemm_bt<false, true><<<dim3(8, 64), 256, 0, stream>>>(
      attp, woutT, d_out, 1024, 1024, ldo, 1024, x);
}

// Round 9
// 223.612 us; speedup vs baseline: 2.4234x; 1.3529x over previous
//
#include <hip/hip_runtime.h>

typedef unsigned short u16;
typedef __attribute__((ext_vector_type(8))) short bh8;     // 8 bf16 MFMA A/B frag
typedef __attribute__((ext_vector_type(4))) float f4;      // MFMA C/D frag / float4
typedef __attribute__((ext_vector_type(4))) unsigned short us4;

#define T_SEQ 2048
#define NHEADS 16
#define DHEAD 64
#define WIN 256

#define MF(a, b, c) __builtin_amdgcn_mfma_f32_16x16x32_bf16((a), (b), (c), 0, 0, 0)

__device__ __forceinline__ float bf2f(u16 u) {
  union { unsigned int i; float f; } v; v.i = ((unsigned int)u) << 16; return v.f;
}
__device__ __forceinline__ u16 f2bf(float f) {
  unsigned int u = __float_as_uint(f);
  u = u + 0x7fffu + ((u >> 16) & 1u);   // RNE
  return (u16)(u >> 16);
}
__device__ __forceinline__ void async16(const void* g, void* l) {
  void* gv = const_cast<void*>(g);
  __builtin_amdgcn_global_load_lds(
      (__attribute__((address_space(1))) void*)gv,
      (__attribute__((address_space(3))) void*)l, 16, 0, 0);
}

// Inline dtype probe: 1 if x[0..255] plausible as fp32. Wave-uniform (ballot).
__device__ __forceinline__ int is_f32_probe(const void* x) {
  const float* xf = (const float*)x;
  const int lane = threadIdx.x & 63;
  int bad = 0;
  #pragma unroll
  for (int u = 0; u < 4; ++u) {
    const float v = xf[lane * 4 + u];
    const float a = fabsf(v);
    bad |= (!(a < 64.f)) || (!(v == 0.f || a > 1e-30f));
  }
  return __any(bad) ? 0 : 1;
}

// ---------------- fused prep: xconv + transpose(w_qkv) + transpose(w_out) ------------
// xconv restored (round-8 showed direct fp32 GEMM reads cost +104 us).
// Transposes vectorized: one f4/us4 load + one us4 store per thread.
__global__ __launch_bounds__(256) void prep(
    const void* __restrict__ x, const void* __restrict__ w_qkv,
    const void* __restrict__ w_out, u16* __restrict__ xbf,
    u16* __restrict__ wqkvT, u16* __restrict__ woutT, int have_x)
{
  const int bid = blockIdx.x;
  const int tid = threadIdx.x;
  const int isf = is_f32_probe(x);

  if (bid < 4096) {                       // ---- xconv ----
    if (!have_x) return;
    const size_t e = ((size_t)bid * 256 + tid) * 8;
    if (isf) {
      const float* f = (const float*)x;
      us4 o0, o1;
      #pragma unroll
      for (int u = 0; u < 4; ++u) { o0[u] = f2bf(f[e + u]); o1[u] = f2bf(f[e + 4 + u]); }
      *(us4*)&xbf[e] = o0; *(us4*)&xbf[e + 4] = o1;
    } else {
      *(us4*)&xbf[e]     = *(const us4*)&((const u16*)x)[e];
      *(us4*)&xbf[e + 4] = *(const us4*)&((const u16*)x)[e + 4];
    }
  } else {                                // ---- transposes ----
    __shared__ alignas(16) u16 tile[32][33];
    const void* in; u16* out; int C, bx, by;
    const int t0 = bid - 4096;
    if (t0 < 3072) { in = w_qkv; out = wqkvT; C = 3072; bx = t0 % 96; by = t0 / 96; }
    else           { const int t = t0 - 3072; in = w_out; out = woutT; C = 1024; bx = t % 32; by = t / 32; }
    const int tx4 = (tid & 7) * 4;
    const int iy  = tid >> 3;
    const int y0 = by * 32;
    if (isf) {
      f4 v = *(const f4*)&((const float*)in)[(size_t)(y0 + iy) * C + bx * 32 + tx4];
      #pragma unroll
      for (int u = 0; u < 4; ++u) tile[iy][tx4 + u] = f2bf(v[u]);
    } else {
      us4 v = *(const us4*)&((const u16*)in)[(size_t)(y0 + iy) * C + bx * 32 + tx4];
      #pragma unroll
      for (int u = 0; u < 4; ++u) tile[iy][tx4 + u] = v[u];
    }
    __syncthreads();
    const int i2 = tid >> 3;
    us4 o;
    #pragma unroll
    for (int u = 0; u < 4; ++u) o[u] = tile[tx4 + u][i2];
    *(us4*)&out[(size_t)(bx * 32 + i2) * 1024 + y0 + tx4] = o;
  }
}

// ---------------- bf16 GEMM, C[M,N] = A[M,K(lda)] * Bt[N,K]^T ----------------
// BK=64; 128 x BN tile (BN=128 or 64). LDS row = 128B (8 chunks of 16B); slot
// (row,c) holds GLOBAL chunk c ^ (row&7) -> conflict-free b128 frag reads.
// BN=64: LDS 24KB -> 6 blocks/CU (vs 4) -- more TLP for the latency-bound
// out-proj shape (1024 blocks, all resident in one pass).
template<int BN, bool ADYN, bool CDYN>
__global__ __launch_bounds__(256, 4) void gemm_bt(
    const void* __restrict__ A, const u16* __restrict__ Bt,
    void* __restrict__ C, int N, int K, int lda, int ldc,
    const void* __restrict__ xprobe)
{
  constexpr int NJ = BN / 32;             // j-frags per wave (4 or 2)
  __shared__ alignas(16) u16 As[128 * 64];
  __shared__ alignas(16) u16 Bs[BN * 64];

  const int isf  = (ADYN || CDYN) ? is_f32_probe(xprobe) : 0;
  const int tid  = threadIdx.x;
  const int lane = tid & 63;
  const int w    = tid >> 6;
  const int wm   = (w >> 1) * 64;
  const int wn   = (w & 1) * (BN / 2);
  const int quad = lane >> 4;
  const int l16  = lane & 15;
  const int row0 = blockIdx.y * 128;
  const int col0 = blockIdx.x * BN;

  f4 acc[4][NJ] = {};

  size_t aoff[4]; const u16* bsrc[NJ]; int lofs[4];
  #pragma unroll
  for (int s = 0; s < 4; ++s) {
    const int r  = s * 32 + (tid >> 3);
    const int gc = (tid & 7) ^ (r & 7);
    aoff[s] = (size_t)(row0 + r) * lda + gc * 8;
    lofs[s] = s * 4096 + tid * 16;
  }
  #pragma unroll
  for (int s = 0; s < NJ; ++s) {
    const int r  = s * 32 + (tid >> 3);
    const int gc = (tid & 7) ^ (r & 7);
    bsrc[s] = Bt + (size_t)(col0 + r) * K + gc * 8;
  }

  const bool af32 = ADYN && isf;

  for (int k0 = 0; k0 < K; k0 += 64) {
    if (af32) {
      const float* Af = (const float*)A;
      bh8 a[4];
      #pragma unroll
      for (int s = 0; s < 4; ++s) {
        f4 u0 = *(const f4*)(Af + aoff[s] + k0);
        f4 u1 = *(const f4*)(Af + aoff[s] + k0 + 4);
        #pragma unroll
        for (int u = 0; u < 4; ++u) { a[s][u] = (short)f2bf(u0[u]); a[s][u + 4] = (short)f2bf(u1[u]); }
      }
      __syncthreads();
      #pragma unroll
      for (int s = 0; s < 4; ++s)
        *(bh8*)((char*)As + lofs[s]) = a[s];
      #pragma unroll
      for (int s = 0; s < NJ; ++s)
        async16(bsrc[s] + k0, (char*)Bs + lofs[s]);
    } else {
      const u16* A16 = (const u16*)A;
      __syncthreads();
      #pragma unroll
      for (int s = 0; s < 4; ++s)
        async16(A16 + aoff[s] + k0, (char*)As + lofs[s]);
      #pragma unroll
      for (int s = 0; s < NJ; ++s)
        async16(bsrc[s] + k0, (char*)Bs + lofs[s]);
    }
    __builtin_amdgcn_s_waitcnt(0);
    __syncthreads();

    #pragma unroll
    for (int ks = 0; ks < 2; ++ks) {
      bh8 af[4], bf[NJ];
      #pragma unroll
      for (int i = 0; i < 4; ++i) {
        const int row = wm + i * 16 + l16;
        const int lc  = (ks * 4 + quad) ^ (row & 7);
        af[i] = *(const bh8*)(As + row * 64 + lc * 8);
      }
      #pragma unroll
      for (int j = 0; j < NJ; ++j) {
        const int row = wn + j * 16 + l16;
        const int lc  = (ks * 4 + quad) ^ (row & 7);
        bf[j] = *(const bh8*)(Bs + row * 64 + lc * 8);
      }
      #pragma unroll
      for (int i = 0; i < 4; ++i)
        #pragma unroll
        for (int j = 0; j < NJ; ++j)
          acc[i][j] = MF(af[i], bf[j], acc[i][j]);
    }
  }

  const bool cf32 = CDYN && isf;
  #pragma unroll
  for (int i = 0; i < 4; ++i) {
    #pragma unroll
    for (int j = 0; j < NJ; ++j) {
      const int rb = row0 + wm + i * 16 + quad * 4;
      const int cc = col0 + wn + j * 16 + l16;
      #pragma unroll
      for (int r = 0; r < 4; ++r) {
        if (cf32) ((float*)C)[(size_t)(rb + r) * ldc + cc] = acc[i][j][r];
        else      ((u16*)C)[(size_t)(rb + r) * ldc + cc]   = f2bf(acc[i][j][r]);
      }
    }
  }
}

// ---------------- MFMA flash-style sliding-window attention ----------------
// Verified round-2 body (211.3 us build). Q frags in registers (pre-scaled by
// 1/sqrt(d)); LDS = Kt+Vt+Ps = 27.6 KB -> 5 blocks/CU. Mask algebra: tiles
// t=1..3 unmasked; t=4 (diag) / t=0 (ledge) reduce to the kb==w sub-tile;
// fully-dead sub-tiles skip their QK MFMAs. Defer-max (T13) on the rescale.
__global__ __launch_bounds__(256) void attn_mfma(const u16* __restrict__ qkv,
                                                 u16* __restrict__ att, int ldo)
{
  __shared__ alignas(16) u16 Kt[64 * 72];
  __shared__ alignas(16) u16 Vt[64 * 72];   // (d,k): d*72 + ((k>>3)^(d>>3))*8 + (k&7)
  __shared__ alignas(16) u16 Ps[64 * 72];   // (q,k): q*72 + ((k>>3)^((q>>3)&1))*8 + (k&7)

  const int tid  = threadIdx.x;
  const int lane = tid & 63;
  const int w    = tid >> 6;
  const int quad = lane >> 4;
  const int l16  = lane & 15;
  const int qb = blockIdx.x, h = blockIdx.y, b = blockIdx.z;
  const int qs = qb * 64;

  const u16* base = qkv + (size_t)b * T_SEQ * 3072 + h * 64;

  const size_t qrowg = (size_t)(qs + w * 16 + l16) * 3072;
  bh8 qa0 = *(const bh8*)&base[qrowg + quad * 8];
  bh8 qa1 = *(const bh8*)&base[qrowg + 32 + quad * 8];
  #pragma unroll
  for (int u = 0; u < 8; ++u) {
    qa0[u] = (short)f2bf(bf2f((u16)qa0[u]) * 0.125f);
    qa1[u] = (short)f2bf(bf2f((u16)qa1[u]) * 0.125f);
  }

  f4 Oc[4] = {};
  float mst[4] = {-1e30f, -1e30f, -1e30f, -1e30f};
  float lst[4] = {0.f, 0.f, 0.f, 0.f};

  const int tmin = (qb >= 4) ? 0 : (4 - qb);
  const int c8  = (tid & 7) * 8;
  const int r0s = tid >> 3;

  for (int t = tmin; t < 5; ++t) {
    const int kt0 = qs - 256 + t * 64;
    const bool diag  = (t == 4);          // only j<=i can fail
    const bool ledge = (t == 0);          // only reached when qb>=4; only j>i-WIN can fail
    const int kb_lo = ledge ? w : 0;      // kb<w fully masked on left edge
    const int kb_hi = diag  ? w : 3;      // kb>w fully masked on diagonal
    __syncthreads();

    #pragma unroll
    for (int r = r0s; r < 64; r += 32) {
      *(bh8*)&Kt[r * 72 + c8] =
          *(const bh8*)&base[(size_t)(kt0 + r) * 3072 + 1024 + c8];
      bh8 v = *(const bh8*)&base[(size_t)(kt0 + r) * 3072 + 2048 + c8];
      const int kc = r >> 3, ki = r & 7;
      #pragma unroll
      for (int u = 0; u < 8; ++u) {
        const int d = c8 + u;
        Vt[d * 72 + ((kc ^ (d >> 3)) << 3) + ki] = (u16)v[u];
      }
    }
    __syncthreads();

    f4 S[4];
    #pragma unroll
    for (int kb = 0; kb < 4; ++kb) {
      if (kb < kb_lo || kb > kb_hi) {
        S[kb][0] = S[kb][1] = S[kb][2] = S[kb][3] = -1e30f;
      } else {
        const int krow = (kb * 16 + l16) * 72;
        bh8 kf0 = *(const bh8*)&Kt[krow + quad * 8];
        bh8 kf1 = *(const bh8*)&Kt[krow + 32 + quad * 8];
        f4 s = {};
        s = MF(qa0, kf0, s);
        s = MF(qa1, kf1, s);
        S[kb] = s;
      }
    }

    if (diag || ledge) {
      #pragma unroll
      for (int kb = 0; kb < 4; ++kb) {
        if (kb == w) {
          #pragma unroll
          for (int rr = 0; rr < 4; ++rr) {
            const int ii = quad * 4 + rr;
            const bool ok = diag ? (l16 <= ii) : (l16 > ii);
            if (!ok) S[kb][rr] = -1e30f;
          }
        }
      }
    }

    float tmax[4] = {-1e30f, -1e30f, -1e30f, -1e30f};
    #pragma unroll
    for (int kb = 0; kb < 4; ++kb)
      #pragma unroll
      for (int rr = 0; rr < 4; ++rr)
        tmax[rr] = fmaxf(tmax[rr], S[kb][rr]);
    #pragma unroll
    for (int off = 1; off < 16; off <<= 1)
      #pragma unroll
      for (int rr = 0; rr < 4; ++rr)
        tmax[rr] = fmaxf(tmax[rr], __shfl_xor(tmax[rr], off));

    // defer-max (T13): skip rescale while the running max grows < 8
    const bool grew = (tmax[0] > mst[0] + 8.f) || (tmax[1] > mst[1] + 8.f) ||
                      (tmax[2] > mst[2] + 8.f) || (tmax[3] > mst[3] + 8.f);
    if (__any(grew)) {
      #pragma unroll
      for (int rr = 0; rr < 4; ++rr) {
        const float mnew = fmaxf(mst[rr], tmax[rr]);
        const float al = __expf(mst[rr] - mnew);
        mst[rr] = mnew;
        lst[rr] *= al;
        #pragma unroll
        for (int db = 0; db < 4; ++db) Oc[db][rr] *= al;
      }
    }

    float rsum[4] = {0.f, 0.f, 0.f, 0.f};
    const int swq = quad >> 1;
    #pragma unroll
    for (int kb = 0; kb < 4; ++kb) {
      const int kc = kb * 2 + (l16 >> 3);
      const int ki = l16 & 7;
      #pragma unroll
      for (int rr = 0; rr < 4; ++rr) {
        const float p = __expf(S[kb][rr] - mst[rr]);  // masked: exp(-1e30)->0
        rsum[rr] += p;
        const int q = w * 16 + quad * 4 + rr;
        Ps[q * 72 + ((kc ^ swq) << 3) + ki] = f2bf(p);
      }
    }
    #pragma unroll
    for (int off = 1; off < 16; off <<= 1)
      #pragma unroll
      for (int rr = 0; rr < 4; ++rr)
        rsum[rr] += __shfl_xor(rsum[rr], off);
    #pragma unroll
    for (int rr = 0; rr < 4; ++rr)
      lst[rr] += rsum[rr];

    {
      const int q = w * 16 + l16;
      const int swp = (q >> 3) & 1;
      bh8 pa0 = *(const bh8*)&Ps[q * 72 + (((0 + quad) ^ swp) << 3)];
      bh8 pa1 = *(const bh8*)&Ps[q * 72 + (((4 + quad) ^ swp) << 3)];
      #pragma unroll
      for (int db = 0; db < 4; ++db) {
        const int d = db * 16 + l16;
        const int dsw = d >> 3;
        bh8 vb0 = *(const bh8*)&Vt[d * 72 + (((0 + quad) ^ dsw) << 3)];
        bh8 vb1 = *(const bh8*)&Vt[d * 72 + (((4 + quad) ^ dsw) << 3)];
        Oc[db] = MF(pa0, vb0, Oc[db]);
        Oc[db] = MF(pa1, vb1, Oc[db]);
      }
    }
  }

  u16* obase = att + (size_t)b * T_SEQ * ldo + h * 64;
  #pragma unroll
  for (int rr = 0; rr < 4; ++rr) {
    const int i = qs + w * 16 + quad * 4 + rr;
    const float inv = 1.f / lst[rr];
    #pragma unroll
    for (int db = 0; db < 4; ++db)
      obase[(size_t)i * ldo + db * 16 + l16] = f2bf(Oc[db][rr] * inv);
  }
}

// ---------------- launcher ----------------
extern "C" void kernel_launch(void* const* d_in, const int* in_sizes, int n_in,
                              void* d_out, int out_size, void* d_ws, size_t ws_size,
                              hipStream_t stream) {
  const void* x     = d_in[0];   // [8192, 1024]  fp32 or bf16 (auto-detected)
  const void* w_qkv = d_in[1];   // [1024, 3072]
  const void* w_out = d_in[2];   // [1024, 1024]

  const size_t SZ_QKV = (size_t)8192 * 3072 * 2;
  const size_t SZ_XBF = (size_t)8192 * 1024 * 2;
  const size_t SZ_WQ  = (size_t)3072 * 1024 * 2;
  const size_t SZ_WO  = (size_t)1024 * 1024 * 2;
  const size_t SZ_ATT = (size_t)8192 * 1024 * 2;

  char* p = (char*)d_ws;
  u16* qkv   = (u16*)p; p += SZ_QKV;
  u16* wqkvT = (u16*)p; p += SZ_WQ;
  u16* woutT = (u16*)p; p += SZ_WO;
  u16* xbf   = (u16*)p; p += SZ_XBF;
  u16* attb  = (u16*)p;
  const size_t need_x   = SZ_QKV + SZ_WQ + SZ_WO + SZ_XBF;
  const bool have_x   = ws_size >= need_x;
  const bool have_att = ws_size >= need_x + SZ_ATT;

  prep<<<dim3(8192), 256, 0, stream>>>(x, w_qkv, w_out, xbf, wqkvT, woutT,
                                       have_x ? 1 : 0);

  if (have_x) {
    gemm_bt<128, false, false><<<dim3(24, 64), 256, 0, stream>>>(
        xbf, wqkvT, qkv, 3072, 1024, 1024, 3072, x);
  } else {
    gemm_bt<128, true, false><<<dim3(24, 64), 256, 0, stream>>>(
        x, wqkvT, qkv, 3072, 1024, 1024, 3072, x);
  }

  // attention: compact output when ws allows, else in-place q-channel
  u16* attp  = have_att ? attb : qkv;
  const int ldo = have_att ? 1024 : 3072;
  attn_mfma<<<dim3(32, NHEADS, 4), 256, 0, stream>>>(qkv, attp, ldo);

  // out-proj: 128x64 tiles -> 1024 blocks, 6 blocks/CU, single resident pass
  gemm_bt<64, false, true><<<dim3(16, 64), 256, 0, stream>>>(
      attp, woutT, d_out, 1024, 1024, ldo, 1024, x);
}

// Round 10
// 218.870 us; speedup vs baseline: 2.4759x; 1.0217x over previous
//
#include <hip/hip_runtime.h>

typedef unsigned short u16;
typedef __attribute__((ext_vector_type(8))) short bh8;     // 8 bf16 MFMA A/B frag
typedef __attribute__((ext_vector_type(4))) float f4;      // MFMA C/D frag / float4
typedef __attribute__((ext_vector_type(4))) unsigned short us4;

#define T_SEQ 2048
#define NHEADS 16
#define DHEAD 64
#define WIN 256

#define MF(a, b, c) __builtin_amdgcn_mfma_f32_16x16x32_bf16((a), (b), (c), 0, 0, 0)
#define VMCNT(n) asm volatile("s_waitcnt vmcnt(" #n ")" ::: "memory")

__device__ __forceinline__ float bf2f(u16 u) {
  union { unsigned int i; float f; } v; v.i = ((unsigned int)u) << 16; return v.f;
}
__device__ __forceinline__ u16 f2bf(float f) {
  unsigned int u = __float_as_uint(f);
  u = u + 0x7fffu + ((u >> 16) & 1u);   // RNE
  return (u16)(u >> 16);
}
__device__ __forceinline__ void async16(const void* g, void* l) {
  void* gv = const_cast<void*>(g);
  __builtin_amdgcn_global_load_lds(
      (__attribute__((address_space(1))) void*)gv,
      (__attribute__((address_space(3))) void*)l, 16, 0, 0);
}

// Inline dtype probe: 1 if x[0..255] plausible as fp32. Wave-uniform (ballot).
__device__ __forceinline__ int is_f32_probe(const void* x) {
  const float* xf = (const float*)x;
  const int lane = threadIdx.x & 63;
  int bad = 0;
  #pragma unroll
  for (int u = 0; u < 4; ++u) {
    const float v = xf[lane * 4 + u];
    const float a = fabsf(v);
    bad |= (!(a < 64.f)) || (!(v == 0.f || a > 1e-30f));
  }
  return __any(bad) ? 0 : 1;
}

// ---------------- fused prep: xconv + transpose(w_qkv) + transpose(w_out) ------------
__global__ __launch_bounds__(256) void prep(
    const void* __restrict__ x, const void* __restrict__ w_qkv,
    const void* __restrict__ w_out, u16* __restrict__ xbf,
    u16* __restrict__ wqkvT, u16* __restrict__ woutT, int have_x)
{
  const int bid = blockIdx.x;
  const int tid = threadIdx.x;
  const int isf = is_f32_probe(x);

  if (bid < 4096) {                       // ---- xconv ----
    if (!have_x) return;
    const size_t e = ((size_t)bid * 256 + tid) * 8;
    if (isf) {
      const float* f = (const float*)x;
      us4 o0, o1;
      #pragma unroll
      for (int u = 0; u < 4; ++u) { o0[u] = f2bf(f[e + u]); o1[u] = f2bf(f[e + 4 + u]); }
      *(us4*)&xbf[e] = o0; *(us4*)&xbf[e + 4] = o1;
    } else {
      *(us4*)&xbf[e]     = *(const us4*)&((const u16*)x)[e];
      *(us4*)&xbf[e + 4] = *(const us4*)&((const u16*)x)[e + 4];
    }
  } else {                                // ---- transposes ----
    __shared__ alignas(16) u16 tile[32][33];
    const void* in; u16* out; int C, bx, by;
    const int t0 = bid - 4096;
    if (t0 < 3072) { in = w_qkv; out = wqkvT; C = 3072; bx = t0 % 96; by = t0 / 96; }
    else           { const int t = t0 - 3072; in = w_out; out = woutT; C = 1024; bx = t % 32; by = t / 32; }
    const int tx4 = (tid & 7) * 4;
    const int iy  = tid >> 3;
    const int y0 = by * 32;
    if (isf) {
      f4 v = *(const f4*)&((const float*)in)[(size_t)(y0 + iy) * C + bx * 32 + tx4];
      #pragma unroll
      for (int u = 0; u < 4; ++u) tile[iy][tx4 + u] = f2bf(v[u]);
    } else {
      us4 v = *(const us4*)&((const u16*)in)[(size_t)(y0 + iy) * C + bx * 32 + tx4];
      #pragma unroll
      for (int u = 0; u < 4; ++u) tile[iy][tx4 + u] = v[u];
    }
    __syncthreads();
    const int i2 = tid >> 3;
    us4 o;
    #pragma unroll
    for (int u = 0; u < 4; ++u) o[u] = tile[tx4 + u][i2];
    *(us4*)&out[(size_t)(bx * 32 + i2) * 1024 + y0 + tx4] = o;
  }
}

// ---------------- bf16 GEMM, C[M,N] = A[M,K(lda)] * Bt[N,K]^T ----------------
// BK=64; 128 x BN tile (BN=128 or 64). LDS row = 128B (8 chunks of 16B); slot
// (row,c) holds GLOBAL chunk c ^ (row&7) -> conflict-free b128 frag reads.
template<int BN, bool ADYN, bool CDYN>
__global__ __launch_bounds__(256, 4) void gemm_bt(
    const void* __restrict__ A, const u16* __restrict__ Bt,
    void* __restrict__ C, int N, int K, int lda, int ldc,
    const void* __restrict__ xprobe)
{
  constexpr int NJ = BN / 32;             // j-frags per wave (4 or 2)
  __shared__ alignas(16) u16 As[128 * 64];
  __shared__ alignas(16) u16 Bs[BN * 64];

  const int isf  = (ADYN || CDYN) ? is_f32_probe(xprobe) : 0;
  const int tid  = threadIdx.x;
  const int lane = tid & 63;
  const int w    = tid >> 6;
  const int wm   = (w >> 1) * 64;
  const int wn   = (w & 1) * (BN / 2);
  const int quad = lane >> 4;
  const int l16  = lane & 15;
  const int row0 = blockIdx.y * 128;
  const int col0 = blockIdx.x * BN;

  f4 acc[4][NJ] = {};

  size_t aoff[4]; const u16* bsrc[NJ]; int lofs[4];
  #pragma unroll
  for (int s = 0; s < 4; ++s) {
    const int r  = s * 32 + (tid >> 3);
    const int gc = (tid & 7) ^ (r & 7);
    aoff[s] = (size_t)(row0 + r) * lda + gc * 8;
    lofs[s] = s * 4096 + tid * 16;
  }
  #pragma unroll
  for (int s = 0; s < NJ; ++s) {
    const int r  = s * 32 + (tid >> 3);
    const int gc = (tid & 7) ^ (r & 7);
    bsrc[s] = Bt + (size_t)(col0 + r) * K + gc * 8;
  }

  const bool af32 = ADYN && isf;

  for (int k0 = 0; k0 < K; k0 += 64) {
    if (af32) {
      const float* Af = (const float*)A;
      bh8 a[4];
      #pragma unroll
      for (int s = 0; s < 4; ++s) {
        f4 u0 = *(const f4*)(Af + aoff[s] + k0);
        f4 u1 = *(const f4*)(Af + aoff[s] + k0 + 4);
        #pragma unroll
        for (int u = 0; u < 4; ++u) { a[s][u] = (short)f2bf(u0[u]); a[s][u + 4] = (short)f2bf(u1[u]); }
      }
      __syncthreads();
      #pragma unroll
      for (int s = 0; s < 4; ++s)
        *(bh8*)((char*)As + lofs[s]) = a[s];
      #pragma unroll
      for (int s = 0; s < NJ; ++s)
        async16(bsrc[s] + k0, (char*)Bs + lofs[s]);
    } else {
      const u16* A16 = (const u16*)A;
      __syncthreads();
      #pragma unroll
      for (int s = 0; s < 4; ++s)
        async16(A16 + aoff[s] + k0, (char*)As + lofs[s]);
      #pragma unroll
      for (int s = 0; s < NJ; ++s)
        async16(bsrc[s] + k0, (char*)Bs + lofs[s]);
    }
    __builtin_amdgcn_s_waitcnt(0);
    __syncthreads();

    #pragma unroll
    for (int ks = 0; ks < 2; ++ks) {
      bh8 af[4], bf[NJ];
      #pragma unroll
      for (int i = 0; i < 4; ++i) {
        const int row = wm + i * 16 + l16;
        const int lc  = (ks * 4 + quad) ^ (row & 7);
        af[i] = *(const bh8*)(As + row * 64 + lc * 8);
      }
      #pragma unroll
      for (int j = 0; j < NJ; ++j) {
        const int row = wn + j * 16 + l16;
        const int lc  = (ks * 4 + quad) ^ (row & 7);
        bf[j] = *(const bh8*)(Bs + row * 64 + lc * 8);
      }
      #pragma unroll
      for (int i = 0; i < 4; ++i)
        #pragma unroll
        for (int j = 0; j < NJ; ++j)
          acc[i][j] = MF(af[i], bf[j], acc[i][j]);
    }
  }

  const bool cf32 = CDYN && isf;
  #pragma unroll
  for (int i = 0; i < 4; ++i) {
    #pragma unroll
    for (int j = 0; j < NJ; ++j) {
      const int rb = row0 + wm + i * 16 + quad * 4;
      const int cc = col0 + wn + j * 16 + l16;
      #pragma unroll
      for (int r = 0; r < 4; ++r) {
        if (cf32) ((float*)C)[(size_t)(rb + r) * ldc + cc] = acc[i][j][r];
        else      ((u16*)C)[(size_t)(rb + r) * ldc + cc]   = f2bf(acc[i][j][r]);
      }
    }
  }
}

// ---------------- MFMA flash-style sliding-window attention ----------------
// Round-9 math/masks/Ps/Vt verbatim; staging restructured:
//  * K staged via global_load_lds into DOUBLE-BUFFERED Kt[2][64x64] (swizzled
//    slot (r,c) holds global chunk c^(r&7) -- layout harness-validated round 4).
//  * Tile t+1's K-stage (2 loads) and V register loads (2 loads) are issued
//    BEFORE tile t's compute; counted VMCNT(4) at the head of each iteration
//    retires everything older (K(t), V(t)) while t+1's 4 loads stay in flight
//    across the whole tile-t compute (first counted vmcnt in this attn).
//  * V scatter-transpose into Vt from registers (T14 async-split write-late).
// LDS: Kt 16KB + Vt 9KB + Ps 9KB = 34.2KB -> 4 blocks/CU.
__global__ __launch_bounds__(256) void attn_mfma(const u16* __restrict__ qkv,
                                                 u16* __restrict__ att, int ldo)
{
  __shared__ alignas(16) u16 Kt[2][64 * 64];
  __shared__ alignas(16) u16 Vt[64 * 72];   // (d,k): d*72 + ((k>>3)^(d>>3))*8 + (k&7)
  __shared__ alignas(16) u16 Ps[64 * 72];   // (q,k): q*72 + ((k>>3)^((q>>3)&1))*8 + (k&7)

  const int tid  = threadIdx.x;
  const int lane = tid & 63;
  const int w    = tid >> 6;
  const int quad = lane >> 4;
  const int l16  = lane & 15;
  const int qb = blockIdx.x, h = blockIdx.y, b = blockIdx.z;
  const int qs = qb * 64;

  const u16* base = qkv + (size_t)b * T_SEQ * 3072 + h * 64;

  // staging geometry: 2 sweeps x 256 thr cover 64 rows x 8 chunks (512 slots)
  const int r0 = tid >> 3;                 // sweep-0 row
  const int r1 = 32 + r0;                  // sweep-1 row
  const int c0 = tid & 7;
  const int gc0 = c0 ^ (r0 & 7);
  const int gc1 = c0 ^ (r1 & 7);
  const int c8  = c0 * 8;                  // V global chunk (unswizzled)

  const int tmin = (qb >= 4) ? 0 : (4 - qb);

  // Q frags, pre-scaled by 0.125 (folds softmax 1/sqrt(64))
  const size_t qrowg = (size_t)(qs + w * 16 + l16) * 3072;
  bh8 qa0 = *(const bh8*)&base[qrowg + quad * 8];
  bh8 qa1 = *(const bh8*)&base[qrowg + 32 + quad * 8];
  #pragma unroll
  for (int u = 0; u < 8; ++u) {
    qa0[u] = (short)f2bf(bf2f((u16)qa0[u]) * 0.125f);
    qa1[u] = (short)f2bf(bf2f((u16)qa1[u]) * 0.125f);
  }

  // prologue: issue K-stage + V-reg loads for tile tmin
  {
    const int kt0 = qs - 256 + tmin * 64;
    async16(&base[(size_t)(kt0 + r0) * 3072 + 1024 + gc0 * 8], (char*)Kt[tmin & 1] + tid * 16);
    async16(&base[(size_t)(kt0 + r1) * 3072 + 1024 + gc1 * 8], (char*)Kt[tmin & 1] + 4096 + tid * 16);
  }
  bh8 vr0, vr1;
  {
    const int kt0 = qs - 256 + tmin * 64;
    vr0 = *(const bh8*)&base[(size_t)(kt0 + r0) * 3072 + 2048 + c8];
    vr1 = *(const bh8*)&base[(size_t)(kt0 + r1) * 3072 + 2048 + c8];
  }

  f4 Oc[4] = {};
  float mst[4] = {-1e30f, -1e30f, -1e30f, -1e30f};
  float lst[4] = {0.f, 0.f, 0.f, 0.f};

  for (int t = tmin; t < 5; ++t) {
    const int kt0 = qs - 256 + t * 64;
    const bool diag  = (t == 4);          // only j<=i can fail
    const bool ledge = (t == 0);          // only reached when qb>=4; only j>i-WIN can fail
    const int kb_lo = ledge ? w : 0;      // kb<w fully masked on left edge
    const int kb_hi = diag  ? w : 3;      // kb>w fully masked on diagonal
    const bool more = (t + 1) < 5;

    // ---- issue tile t+1's loads FIRST (stay in flight across this tile)
    bh8 vn0, vn1;
    if (more) {
      const int kn0 = kt0 + 64;
      async16(&base[(size_t)(kn0 + r0) * 3072 + 1024 + gc0 * 8], (char*)Kt[(t + 1) & 1] + tid * 16);
      async16(&base[(size_t)(kn0 + r1) * 3072 + 1024 + gc1 * 8], (char*)Kt[(t + 1) & 1] + 4096 + tid * 16);
      vn0 = *(const bh8*)&base[(size_t)(kn0 + r0) * 3072 + 2048 + c8];
      vn1 = *(const bh8*)&base[(size_t)(kn0 + r1) * 3072 + 2048 + c8];
    }
    // counted wait: allow t+1's 4 loads outstanding; K(t)/V(t) retired
    if (more) { VMCNT(4); } else { VMCNT(0); }
    __syncthreads();                       // Vt free (prev PV done) + K(t) visible

    // ---- V(t) scatter-transpose from registers (write-late)
    {
      const int kc0 = r0 >> 3, ki0 = r0 & 7;
      const int kc1 = r1 >> 3, ki1 = r1 & 7;
      #pragma unroll
      for (int u = 0; u < 8; ++u) {
        const int d = c8 + u;
        Vt[d * 72 + ((kc0 ^ (d >> 3)) << 3) + ki0] = (u16)vr0[u];
        Vt[d * 72 + ((kc1 ^ (d >> 3)) << 3) + ki1] = (u16)vr1[u];
      }
    }
    __syncthreads();

    const u16* Kb = Kt[t & 1];
    f4 S[4];
    #pragma unroll
    for (int kb = 0; kb < 4; ++kb) {
      if (kb < kb_lo || kb > kb_hi) {
        S[kb][0] = S[kb][1] = S[kb][2] = S[kb][3] = -1e30f;
      } else {
        const int row = kb * 16 + l16;
        bh8 kf0 = *(const bh8*)&Kb[row * 64 + (((quad    ) ^ (row & 7)) << 3)];
        bh8 kf1 = *(const bh8*)&Kb[row * 64 + (((quad + 4) ^ (row & 7)) << 3)];
        f4 s = {};
        s = MF(qa0, kf0, s);
        s = MF(qa1, kf1, s);
        S[kb] = s;
      }
    }

    // mask: only the kb==w sub-tile of a masked tile has mixed elements
    if (diag || ledge) {
      #pragma unroll
      for (int kb = 0; kb < 4; ++kb) {
        if (kb == w) {
          #pragma unroll
          for (int rr = 0; rr < 4; ++rr) {
            const int ii = quad * 4 + rr;
            const bool ok = diag ? (l16 <= ii) : (l16 > ii);
            if (!ok) S[kb][rr] = -1e30f;
          }
        }
      }
    }

    float tmax[4] = {-1e30f, -1e30f, -1e30f, -1e30f};
    #pragma unroll
    for (int kb = 0; kb < 4; ++kb)
      #pragma unroll
      for (int rr = 0; rr < 4; ++rr)
        tmax[rr] = fmaxf(tmax[rr], S[kb][rr]);
    #pragma unroll
    for (int off = 1; off < 16; off <<= 1)
      #pragma unroll
      for (int rr = 0; rr < 4; ++rr)
        tmax[rr] = fmaxf(tmax[rr], __shfl_xor(tmax[rr], off));

    // defer-max (T13): skip rescale while the running max grows < 8
    const bool grew = (tmax[0] > mst[0] + 8.f) || (tmax[1] > mst[1] + 8.f) ||
                      (tmax[2] > mst[2] + 8.f) || (tmax[3] > mst[3] + 8.f);
    if (__any(grew)) {
      #pragma unroll
      for (int rr = 0; rr < 4; ++rr) {
        const float mnew = fmaxf(mst[rr], tmax[rr]);
        const float al = __expf(mst[rr] - mnew);
        mst[rr] = mnew;
        lst[rr] *= al;
        #pragma unroll
        for (int db = 0; db < 4; ++db) Oc[db][rr] *= al;
      }
    }

    float rsum[4] = {0.f, 0.f, 0.f, 0.f};
    const int swq = quad >> 1;
    #pragma unroll
    for (int kb = 0; kb < 4; ++kb) {
      const int kc = kb * 2 + (l16 >> 3);
      const int ki = l16 & 7;
      #pragma unroll
      for (int rr = 0; rr < 4; ++rr) {
        const float p = __expf(S[kb][rr] - mst[rr]);  // masked: exp(-1e30)->0
        rsum[rr] += p;
        const int q = w * 16 + quad * 4 + rr;
        Ps[q * 72 + ((kc ^ swq) << 3) + ki] = f2bf(p);
      }
    }
    #pragma unroll
    for (int off = 1; off < 16; off <<= 1)
      #pragma unroll
      for (int rr = 0; rr < 4; ++rr)
        rsum[rr] += __shfl_xor(rsum[rr], off);
    #pragma unroll
    for (int rr = 0; rr < 4; ++rr)
      lst[rr] += rsum[rr];

    {
      const int q = w * 16 + l16;
      const int swp = (q >> 3) & 1;
      bh8 pa0 = *(const bh8*)&Ps[q * 72 + (((0 + quad) ^ swp) << 3)];
      bh8 pa1 = *(const bh8*)&Ps[q * 72 + (((4 + quad) ^ swp) << 3)];
      #pragma unroll
      for (int db = 0; db < 4; ++db) {
        const int d = db * 16 + l16;
        const int dsw = d >> 3;
        bh8 vb0 = *(const bh8*)&Vt[d * 72 + (((0 + quad) ^ dsw) << 3)];
        bh8 vb1 = *(const bh8*)&Vt[d * 72 + (((4 + quad) ^ dsw) << 3)];
        Oc[db] = MF(pa0, vb0, Oc[db]);
        Oc[db] = MF(pa1, vb1, Oc[db]);
      }
    }
    vr0 = vn0; vr1 = vn1;
  }

  u16* obase = att + (size_t)b * T_SEQ * ldo + h * 64;
  #pragma unroll
  for (int rr = 0; rr < 4; ++rr) {
    const int i = qs + w * 16 + quad * 4 + rr;
    const float inv = 1.f / lst[rr];
    #pragma unroll
    for (int db = 0; db < 4; ++db)
      obase[(size_t)i * ldo + db * 16 + l16] = f2bf(Oc[db][rr] * inv);
  }
}

// ---------------- launcher ----------------
extern "C" void kernel_launch(void* const* d_in, const int* in_sizes, int n_in,
                              void* d_out, int out_size, void* d_ws, size_t ws_size,
                              hipStream_t stream) {
  const void* x     = d_in[0];   // [8192, 1024]  fp32 or bf16 (auto-detected)
  const void* w_qkv = d_in[1];   // [1024, 3072]
  const void* w_out = d_in[2];   // [1024, 1024]

  const size_t SZ_QKV = (size_t)8192 * 3072 * 2;
  const size_t SZ_XBF = (size_t)8192 * 1024 * 2;
  const size_t SZ_WQ  = (size_t)3072 * 1024 * 2;
  const size_t SZ_WO  = (size_t)1024 * 1024 * 2;

  char* p = (char*)d_ws;
  u16* qkv   = (u16*)p; p += SZ_QKV;
  u16* wqkvT = (u16*)p; p += SZ_WQ;
  u16* woutT = (u16*)p; p += SZ_WO;
  u16* xbf   = (u16*)p; p += SZ_XBF;
  const size_t need_x = SZ_QKV + SZ_WQ + SZ_WO + SZ_XBF;
  const bool have_x   = ws_size >= need_x;

  prep<<<dim3(8192), 256, 0, stream>>>(x, w_qkv, w_out, xbf, wqkvT, woutT,
                                       have_x ? 1 : 0);

  if (have_x) {
    gemm_bt<128, false, false><<<dim3(24, 64), 256, 0, stream>>>(
        xbf, wqkvT, qkv, 3072, 1024, 1024, 3072, x);
  } else {
    gemm_bt<128, true, false><<<dim3(24, 64), 256, 0, stream>>>(
        x, wqkvT, qkv, 3072, 1024, 1024, 3072, x);
  }

  // attention output aliases xbf (dead after QKV gemm) -> no extra ws needed
  u16* attp  = have_x ? xbf : qkv;
  const int ldo = have_x ? 1024 : 3072;
  attn_mfma<<<dim3(32, NHEADS, 4), 256, 0, stream>>>(qkv, attp, ldo);

  gemm_bt<64, false, true><<<dim3(16, 64), 256, 0, stream>>>(
      attp, woutT, d_out, 1024, 1024, ldo, 1024, x);
}